// Round 1
// baseline (321.064 us; speedup 1.0000x reference)
//
#include <hip/hip_runtime.h>

#define NUM_GRAPHS 512
#define N_NODES 100000
#define N_EDGES 1600000
#define D_NODE 128
#define D_EDGE 32
#define D_OUT 64

#define NB_EDGE 256        // blocks in edge-partial kernel (one 64KB LDS histogram each)
#define EDGE_THREADS 512   // 8 waves/block

// ---------------- kernel 1: node aggregate (batch is sorted -> binary search) ----------
__global__ __launch_bounds__(512) void node_agg_kernel(const float* __restrict__ x,
                                                       const int* __restrict__ batch,
                                                       float* __restrict__ node_agg) {
    const int g = blockIdx.x;
    // all threads redundantly binary-search (batch is cached; uniform path)
    int l = 0, r = N_NODES;
    while (l < r) { int m = (l + r) >> 1; if (batch[m] < g) l = m + 1; else r = m; }
    const int lo = l;
    r = N_NODES;
    while (l < r) { int m = (l + r) >> 1; if (batch[m] < g + 1) l = m + 1; else r = m; }
    const int hi = l;

    const int t = threadIdx.x;
    const int d = t & 127;   // column
    const int rr = t >> 7;   // 0..3 row phase
    float acc = 0.f;
    for (int i = lo + rr; i < hi; i += 4)
        acc += x[(size_t)i * D_NODE + d];

    __shared__ float red[512];
    red[t] = acc;
    __syncthreads();
    if (t < 128) {
        float s = red[t] + red[t + 128] + red[t + 256] + red[t + 384];
        node_agg[g * D_NODE + t] = s;
    }
}

// ---------------- kernel 2: edge partial histograms (LDS-privatized) ------------------
__global__ __launch_bounds__(EDGE_THREADS) void edge_partial_kernel(
        const float* __restrict__ edge_attr,
        const int* __restrict__ col,
        const int* __restrict__ batch,
        float* __restrict__ part) {
    __shared__ float acc[NUM_GRAPHS * D_EDGE];   // 64 KB
    const int t = threadIdx.x;
    for (int i = t; i < NUM_GRAPHS * D_EDGE; i += EDGE_THREADS) acc[i] = 0.f;
    __syncthreads();

    const int EPG = EDGE_THREADS / D_EDGE;       // 16 edges per block-iteration
    const int sub = t >> 5;                      // which edge in the group
    const int d = t & 31;                        // edge-attr column
    const int ngrp = N_EDGES / EPG;              // 100000 exactly

    for (int grp = blockIdx.x; grp < ngrp; grp += gridDim.x) {
        const int e = grp * EPG + sub;
        const int c = col[e];                    // broadcast load within 32-lane group
        const int g = batch[c];                  // gather, L2-resident (400 KB)
        const float v = edge_attr[(size_t)e * D_EDGE + d];  // coalesced 128B/edge
        atomicAdd(&acc[g * D_EDGE + d], v);      // LDS atomic; 2 edges/wave -> 2-way bank alias (free)
    }
    __syncthreads();

    float* dst = part + (size_t)blockIdx.x * (NUM_GRAPHS * D_EDGE);
    for (int i = t; i < NUM_GRAPHS * D_EDGE; i += EDGE_THREADS) dst[i] = acc[i];
}

// ---------------- kernel 3: reduce partials + tiny GEMM -------------------------------
__global__ __launch_bounds__(256) void reduce_gemm_kernel(
        const float* __restrict__ part,
        const float* __restrict__ node_agg,
        const float* __restrict__ W,
        const float* __restrict__ b,
        float* __restrict__ out) {
    const int g = blockIdx.x;
    const int t = threadIdx.x;
    __shared__ float eacc[8][D_EDGE];
    __shared__ float e_final[D_EDGE];
    __shared__ float n_lds[D_NODE];

    const int d = t & 31;
    const int c = t >> 5;                        // 0..7
    float s = 0.f;
    const int PPC = NB_EDGE / 8;                 // partials per chunk
    for (int q = 0; q < PPC; ++q) {
        const int p = c * PPC + q;
        s += part[(size_t)p * (NUM_GRAPHS * D_EDGE) + g * D_EDGE + d];
    }
    eacc[c][d] = s;
    if (t < D_NODE) n_lds[t] = node_agg[g * D_NODE + t];
    __syncthreads();

    if (t < D_EDGE) {
        float v = 0.f;
        #pragma unroll
        for (int cc = 0; cc < 8; ++cc) v += eacc[cc][t];
        e_final[t] = v;
    }
    __syncthreads();

    if (t < D_OUT) {
        float o = b[t];
        #pragma unroll 8
        for (int k = 0; k < D_NODE; ++k) o += n_lds[k] * W[k * D_OUT + t];
        #pragma unroll 8
        for (int k = 0; k < D_EDGE; ++k) o += e_final[k] * W[(D_NODE + k) * D_OUT + t];
        out[g * D_OUT + t] = o;
    }
}

extern "C" void kernel_launch(void* const* d_in, const int* in_sizes, int n_in,
                              void* d_out, int out_size, void* d_ws, size_t ws_size,
                              hipStream_t stream) {
    const float* x         = (const float*)d_in[0];
    const int*   edge_index= (const int*)d_in[1];
    const float* edge_attr = (const float*)d_in[2];
    // d_in[3] = u, unused by the reference output
    const int*   batch     = (const int*)d_in[4];
    const float* W         = (const float*)d_in[5];
    const float* b         = (const float*)d_in[6];
    float* out = (float*)d_out;

    const int* col = edge_index + N_EDGES;   // row 1 of edge_index

    // workspace layout
    float* node_agg = (float*)d_ws;                                   // 512*128 floats = 256 KB
    float* part     = node_agg + (size_t)NUM_GRAPHS * D_NODE;         // NB_EDGE * 512*32 floats = 16 MB

    node_agg_kernel<<<NUM_GRAPHS, 512, 0, stream>>>(x, batch, node_agg);
    edge_partial_kernel<<<NB_EDGE, EDGE_THREADS, 0, stream>>>(edge_attr, col, batch, part);
    reduce_gemm_kernel<<<NUM_GRAPHS, 256, 0, stream>>>(part, node_agg, W, b, out);
}

// Round 2
// 296.672 us; speedup vs baseline: 1.0822x; 1.0822x over previous
//
#include <hip/hip_runtime.h>

#define NUM_GRAPHS 512
#define N_NODES 100000
#define N_EDGES 1600000
#define D_NODE 128
#define D_EDGE 32
#define D_OUT 64

#define NB_EDGE 256        // blocks in edge-partial kernel (one 64KB LDS histogram each)
#define EB_THREADS 1024    // 16 waves/block

// ---------------- kernel 0: eg[e] = batch[col[e]] (streaming, int4) -------------------
__global__ __launch_bounds__(256) void eg_kernel(const int* __restrict__ col,
                                                 const int* __restrict__ batch,
                                                 int* __restrict__ eg) {
    const int i = (blockIdx.x * 256 + threadIdx.x) * 4;
    if (i + 3 < N_EDGES) {
        int4 c = *reinterpret_cast<const int4*>(col + i);
        int g0 = batch[c.x];     // 4 independent gathers, batch is L2-resident (400 KB)
        int g1 = batch[c.y];
        int g2 = batch[c.z];
        int g3 = batch[c.w];
        *reinterpret_cast<int4*>(eg + i) = make_int4(g0, g1, g2, g3);
    } else if (i < N_EDGES) {
        for (int j = i; j < N_EDGES; ++j) eg[j] = batch[col[j]];
    }
}

// ---------------- kernel 1: node aggregate (batch sorted -> binary search, float4) ----
__global__ __launch_bounds__(512) void node_agg_kernel(const float* __restrict__ x,
                                                       const int* __restrict__ batch,
                                                       float* __restrict__ node_agg) {
    const int g = blockIdx.x;
    int l = 0, r = N_NODES;
    while (l < r) { int m = (l + r) >> 1; if (batch[m] < g) l = m + 1; else r = m; }
    const int lo = l;
    r = N_NODES;
    while (l < r) { int m = (l + r) >> 1; if (batch[m] < g + 1) l = m + 1; else r = m; }
    const int hi = l;

    const int t = threadIdx.x;
    const int d4 = t & 31;   // float4 column (32 * 4 = 128 floats)
    const int rr = t >> 5;   // 0..15 row phase
    const float4* x4 = reinterpret_cast<const float4*>(x);

    float4 a = make_float4(0.f, 0.f, 0.f, 0.f);
    for (int i = lo + rr; i < hi; i += 16) {
        float4 v = x4[(size_t)i * 32 + d4];
        a.x += v.x; a.y += v.y; a.z += v.z; a.w += v.w;
    }

    __shared__ float4 red[512];
    red[t] = a;
    __syncthreads();
    if (t < 32) {
        float4 s = red[t];
        #pragma unroll
        for (int p = 1; p < 16; ++p) {
            float4 v = red[p * 32 + t];
            s.x += v.x; s.y += v.y; s.z += v.z; s.w += v.w;
        }
        reinterpret_cast<float4*>(node_agg)[g * 32 + t] = s;
    }
}

// ---------------- kernel 2: edge partial histograms (LDS-privatized, unrolled) --------
__global__ __launch_bounds__(EB_THREADS) void edge_partial_kernel(
        const float* __restrict__ edge_attr,
        const int* __restrict__ eg,
        float* __restrict__ part) {
    __shared__ float acc[NUM_GRAPHS * D_EDGE];   // 64 KB
    const int t = threadIdx.x;
    for (int i = t; i < NUM_GRAPHS * D_EDGE; i += EB_THREADS) acc[i] = 0.f;
    __syncthreads();

    const int EPG = EB_THREADS / D_EDGE;         // 32 edges per block-iteration
    const int sub = t >> 5;                      // which edge in the group (0..31)
    const int d = t & 31;                        // edge-attr column
    const int ngrp = N_EDGES / EPG;              // 50000 exactly
    const int chunk = (ngrp + gridDim.x - 1) / gridDim.x;
    const int gbeg = blockIdx.x * chunk;
    const int gend = min(ngrp, gbeg + chunk);

    int grp = gbeg;
    for (; grp + 4 <= gend; grp += 4) {
        const int e0 = (grp + 0) * EPG + sub;
        const int e1 = e0 + EPG, e2 = e1 + EPG, e3 = e2 + EPG;
        // all 8 loads independent -> deep MLP
        const int g0 = eg[e0], g1 = eg[e1], g2 = eg[e2], g3 = eg[e3];
        const float v0 = edge_attr[(size_t)e0 * D_EDGE + d];
        const float v1 = edge_attr[(size_t)e1 * D_EDGE + d];
        const float v2 = edge_attr[(size_t)e2 * D_EDGE + d];
        const float v3 = edge_attr[(size_t)e3 * D_EDGE + d];
        atomicAdd(&acc[g0 * D_EDGE + d], v0);    // bank = d -> 2-way alias only (free)
        atomicAdd(&acc[g1 * D_EDGE + d], v1);
        atomicAdd(&acc[g2 * D_EDGE + d], v2);
        atomicAdd(&acc[g3 * D_EDGE + d], v3);
    }
    for (; grp < gend; ++grp) {
        const int e = grp * EPG + sub;
        const int g = eg[e];
        atomicAdd(&acc[g * D_EDGE + d], edge_attr[(size_t)e * D_EDGE + d]);
    }
    __syncthreads();

    float* dst = part + (size_t)blockIdx.x * (NUM_GRAPHS * D_EDGE);
    for (int i = t; i < NUM_GRAPHS * D_EDGE; i += EB_THREADS) dst[i] = acc[i];
}

// ---------------- kernel 3: reduce partials + tiny GEMM -------------------------------
__global__ __launch_bounds__(256) void reduce_gemm_kernel(
        const float* __restrict__ part,
        const float* __restrict__ node_agg,
        const float* __restrict__ W,
        const float* __restrict__ b,
        float* __restrict__ out) {
    const int g = blockIdx.x;
    const int t = threadIdx.x;
    __shared__ float eacc[8][D_EDGE];
    __shared__ float e_final[D_EDGE];
    __shared__ float n_lds[D_NODE];

    const int d = t & 31;
    const int c = t >> 5;                        // 0..7
    float s = 0.f;
    const int PPC = NB_EDGE / 8;                 // partials per chunk
    for (int q = 0; q < PPC; ++q) {
        const int p = c * PPC + q;
        s += part[(size_t)p * (NUM_GRAPHS * D_EDGE) + g * D_EDGE + d];
    }
    eacc[c][d] = s;
    if (t < D_NODE) n_lds[t] = node_agg[g * D_NODE + t];
    __syncthreads();

    if (t < D_EDGE) {
        float v = 0.f;
        #pragma unroll
        for (int cc = 0; cc < 8; ++cc) v += eacc[cc][t];
        e_final[t] = v;
    }
    __syncthreads();

    if (t < D_OUT) {
        float o = b[t];
        #pragma unroll 8
        for (int k = 0; k < D_NODE; ++k) o += n_lds[k] * W[k * D_OUT + t];
        #pragma unroll 8
        for (int k = 0; k < D_EDGE; ++k) o += e_final[k] * W[(D_NODE + k) * D_OUT + t];
        out[g * D_OUT + t] = o;
    }
}

extern "C" void kernel_launch(void* const* d_in, const int* in_sizes, int n_in,
                              void* d_out, int out_size, void* d_ws, size_t ws_size,
                              hipStream_t stream) {
    const float* x          = (const float*)d_in[0];
    const int*   edge_index = (const int*)d_in[1];
    const float* edge_attr  = (const float*)d_in[2];
    // d_in[3] = u, unused by the reference output
    const int*   batch      = (const int*)d_in[4];
    const float* W          = (const float*)d_in[5];
    const float* b          = (const float*)d_in[6];
    float* out = (float*)d_out;

    const int* col = edge_index + N_EDGES;   // row 1 of edge_index

    // workspace layout
    float* node_agg = (float*)d_ws;                                    // 256 KB
    float* part     = node_agg + (size_t)NUM_GRAPHS * D_NODE;          // 16 MB
    int*   eg       = (int*)(part + (size_t)NB_EDGE * NUM_GRAPHS * D_EDGE); // 6.4 MB

    const int eg_blocks = (N_EDGES / 4 + 255) / 256;                   // 1563
    eg_kernel<<<eg_blocks, 256, 0, stream>>>(col, batch, eg);
    node_agg_kernel<<<NUM_GRAPHS, 512, 0, stream>>>(x, batch, node_agg);
    edge_partial_kernel<<<NB_EDGE, EB_THREADS, 0, stream>>>(edge_attr, eg, part);
    reduce_gemm_kernel<<<NUM_GRAPHS, 256, 0, stream>>>(part, node_agg, W, b, out);
}